// Round 2
// baseline (1925.053 us; speedup 1.0000x reference)
//
#include <hip/hip_runtime.h>
#include <math.h>
#include <stdint.h>

// ---------------------------------------------------------------------------
// Threefry2x32 (JAX-compatible) and gumbel mapping  (identical to round 0 —
// validated bit-exact enough: absmax 0.0117 vs threshold 0.0263)
// ---------------------------------------------------------------------------
__device__ __forceinline__ uint32_t rotl32(uint32_t v, int r) {
    return (v << r) | (v >> (32 - r));
}

__device__ __forceinline__ void threefry2x32(uint32_t k0, uint32_t k1,
                                             uint32_t& x0, uint32_t& x1) {
    uint32_t ks[3] = {k0, k1, k0 ^ k1 ^ 0x1BD11BDAu};
    const int rot[2][4] = {{13, 15, 26, 6}, {17, 29, 16, 24}};
    x0 += ks[0];
    x1 += ks[1];
#pragma unroll
    for (int i = 0; i < 5; ++i) {
#pragma unroll
        for (int r = 0; r < 4; ++r) {
            x0 += x1;
            x1 = rotl32(x1, rot[i & 1][r]);
            x1 ^= x0;
        }
        x0 += ks[(i + 1) % 3];
        x1 += ks[(i + 2) % 3] + (uint32_t)(i + 1);
    }
}

__device__ __forceinline__ float gumbel_from_bits(uint32_t bits) {
    uint32_t fb = (bits >> 9) | 0x3f800000u;
    float u = __uint_as_float(fb) - 1.0f;
    const float tiny = 1.1754943508222875e-38f;
    u = u * (1.0f - tiny) + tiny;
    u = fmaxf(tiny, u);
    return -logf(-logf(u));
}

__device__ __forceinline__ float softplus_f(float x) {
    return fmaxf(x, 0.0f) + log1pf(expf(-fabsf(x)));
}

// ---------------------------------------------------------------------------
// GEMM: C = X * X^T (unchanged this round)
// ---------------------------------------------------------------------------
#define BM 128
#define BN 128
#define BKK 16

__global__ __launch_bounds__(256) void gemm_xxt(const float* __restrict__ X,
                                                float* __restrict__ C,
                                                int n, int K) {
    __shared__ float As[BKK][BM];
    __shared__ float Bs[BKK][BN];
    const int tid = threadIdx.x;
    const int tx = tid & 15;
    const int ty = tid >> 4;
    const int bm = blockIdx.y * BM;
    const int bn = blockIdx.x * BN;

    float acc[8][8];
#pragma unroll
    for (int p = 0; p < 8; ++p)
#pragma unroll
        for (int q = 0; q < 8; ++q) acc[p][q] = 0.0f;

    for (int k0 = 0; k0 < K; k0 += BKK) {
        for (int l = tid; l < BM * BKK / 4; l += 256) {
            int m = l >> 2;
            int kq = (l & 3) << 2;
            const float4 v = *(const float4*)(X + (size_t)(bm + m) * K + k0 + kq);
            As[kq + 0][m] = v.x; As[kq + 1][m] = v.y;
            As[kq + 2][m] = v.z; As[kq + 3][m] = v.w;
        }
        for (int l = tid; l < BN * BKK / 4; l += 256) {
            int m = l >> 2;
            int kq = (l & 3) << 2;
            const float4 v = *(const float4*)(X + (size_t)(bn + m) * K + k0 + kq);
            Bs[kq + 0][m] = v.x; Bs[kq + 1][m] = v.y;
            Bs[kq + 2][m] = v.z; Bs[kq + 3][m] = v.w;
        }
        __syncthreads();
#pragma unroll
        for (int kk = 0; kk < BKK; ++kk) {
            float a[8], b[8];
#pragma unroll
            for (int p = 0; p < 8; ++p) a[p] = As[kk][p * 16 + ty];
#pragma unroll
            for (int q = 0; q < 8; ++q) b[q] = Bs[kk][q * 16 + tx];
#pragma unroll
            for (int p = 0; p < 8; ++p)
#pragma unroll
                for (int q = 0; q < 8; ++q)
                    acc[p][q] = fmaf(a[p], b[q], acc[p][q]);
        }
        __syncthreads();
    }

    for (int p = 0; p < 8; ++p) {
        int r = bm + p * 16 + ty;
        for (int q = 0; q < 8; ++q) {
            C[(size_t)r * n + bn + q * 16 + tx] = acc[p][q];
        }
    }
}

// ---------------------------------------------------------------------------
// Per-row kernel v2: one wave per row, 4096 elems in 64 VGPRs/lane.
// Register bitonic sort (shuffles for stride>=64), wave-butterfly reductions,
// zero LDS, zero barriers. Slot s = lane*64 + r.
// ---------------------------------------------------------------------------
#define NROW 4096
#define NEGN 4088
#define KCLS 8
#define HHALF 8372224u

__global__ __launch_bounds__(256) void row_kernel(const float* __restrict__ sim,
                                                  float* __restrict__ row_out) {
    const int lane = threadIdx.x & 63;
    const int wv = threadIdx.x >> 6;
    const int row = blockIdx.x * 4 + wv;
    const float* simrow = sim + (size_t)row * NROW;
    const int base = row & ~(KCLS - 1);

    float v[64];
    float nsum = 0.0f, psum = 0.0f, plos = 0.0f, pmax = -INFINITY;

    // ---- load: slot s = lane*64 + rq*4 + c  holds col = rq*256 + lane*4 + c
#pragma unroll
    for (int rq = 0; rq < 16; ++rq) {
        const float4 w4 = *(const float4*)(simrow + rq * 256 + lane * 4);
        float e[4] = {w4.x, w4.y, w4.z, w4.w};
#pragma unroll
        for (int c = 0; c < 4; ++c) {
            int col = rq * 256 + lane * 4 + c;
            float val = e[c];
            bool ispos = (col >= base) && (col < base + KCLS);
            if (ispos) {
                if (col != row) {
                    psum += val;
                    pmax = fmaxf(pmax, val);
                    plos += softplus_f(-2.0f * (val - 0.5f));
                }
                v[rq * 4 + c] = INFINITY;
            } else {
                nsum += val;
                v[rq * 4 + c] = val;
            }
        }
    }

    // ---- wave butterfly reductions for load-phase stats
#pragma unroll
    for (int off = 1; off < 64; off <<= 1) {
        nsum += __shfl_xor(nsum, off, 64);
        psum += __shfl_xor(psum, off, 64);
        plos += __shfl_xor(plos, off, 64);
        pmax = fmaxf(pmax, __shfl_xor(pmax, off, 64));
    }
    const float m = nsum / (float)NEGN;

    // ---- register bitonic sort, ascending over s = lane*64 + r
#pragma unroll
    for (int kk = 2; kk <= 4096; kk <<= 1) {
#pragma unroll
        for (int jj = kk >> 1; jj > 0; jj >>= 1) {
            if (jj >= 64) {
                const int L = jj >> 6;                       // lane xor mask
                const bool asc = (lane & (kk >> 6)) == 0;    // kk >= 128 here
                const bool keepmin = ((lane & L) == 0) == asc;
#pragma unroll
                for (int r = 0; r < 64; ++r) {
                    float b = __shfl_xor(v[r], L, 64);
                    float mn = fminf(v[r], b);
                    float mx = fmaxf(v[r], b);
                    v[r] = keepmin ? mn : mx;
                }
            } else {
#pragma unroll
                for (int r = 0; r < 64; ++r) {
                    if ((r & jj) == 0) {
                        const int r2 = r | jj;
                        bool asc;
                        if (kk >= 128)      asc = (lane & (kk >> 6)) == 0;
                        else if (kk == 64)  asc = (lane & 1) == 0;
                        else                asc = (r & kk) == 0;
                        float a = v[r], b = v[r2];
                        float mn = fminf(a, b), mx = fmaxf(a, b);
                        v[r]  = asc ? mn : mx;
                        v[r2] = asc ? mx : mn;
                    }
                }
            }
        }
    }

    // ---- variance over sorted negatives (positions 0..NEGN-1)
    float vs = 0.0f;
#pragma unroll
    for (int r = 0; r < 64; ++r) {
        bool valid = (r < 56) || (lane < 63);   // s = lane*64+r < 4088
        float d = v[r] - m;
        vs += valid ? d * d : 0.0f;
    }
#pragma unroll
    for (int off = 1; off < 64; off <<= 1) vs += __shfl_xor(vs, off, 64);
    const float var = vs / (float)NEGN;
    const float sd = sqrtf(var);
    const float denom = 2.0f * sd * sd;

    // ---- scores: lp(sorted val) + gumbel(sorted position)
    float sc[64];
    const bool lohalf = (row < 2048);
#pragma unroll
    for (int r = 0; r < 64; ++r) {
        bool valid = (r < 56) || (lane < 63);
        uint32_t f = (uint32_t)(row * NEGN + lane * 64 + r);
        uint32_t x0 = lohalf ? f : f - HHALF;
        uint32_t x1 = lohalf ? f + HHALF : f;
        threefry2x32(0u, 42u, x0, x1);
        float g = gumbel_from_bits(lohalf ? x0 : x1);
        float d = v[r] - m;
        sc[r] = valid ? (d * d) / denom + g : -INFINITY;
    }

    // ---- top-7 by repeated wave argmax (tie-break lower index == lax.top_k)
    float nl = 0.0f, neg_last = 0.0f;
    for (int t = 0; t < 7; ++t) {
        float bs = -INFINITY, bv = 0.0f;
        int bi = 0x7fffffff;
#pragma unroll
        for (int r = 0; r < 64; ++r) {
            if (sc[r] > bs) { bs = sc[r]; bv = v[r]; bi = lane * 64 + r; }
        }
#pragma unroll
        for (int off = 1; off < 64; off <<= 1) {
            float os = __shfl_xor(bs, off, 64);
            float ov = __shfl_xor(bv, off, 64);
            int   oi = __shfl_xor(bi, off, 64);
            if (os > bs || (os == bs && oi < bi)) { bs = os; bv = ov; bi = oi; }
        }
        nl += softplus_f(50.0f * (bv - 0.5f));
        if (t == 6) neg_last = bv;
#pragma unroll
        for (int r = 0; r < 64; ++r) {
            if (lane * 64 + r == bi) sc[r] = -INFINITY;
        }
    }

    if (lane == 0) {
        float pos_loss = plos / (float)(KCLS - 1);
        float neg_loss = 0.04f * (nl / (float)(KCLS - 1));
        row_out[row * 4 + 0] = pos_loss + neg_loss;
        row_out[row * 4 + 1] = (pmax > neg_last + 0.05f) ? 1.0f : 0.0f;
        row_out[row * 4 + 2] = psum;
        row_out[row * 4 + 3] = nsum;
    }
}

// ---------------------------------------------------------------------------
// Deterministic final reduction (single block, f64 accumulation)
// ---------------------------------------------------------------------------
__global__ __launch_bounds__(256) void reduce_kernel(const float* __restrict__ row_out,
                                                     float* __restrict__ out,
                                                     int n, int k) {
    __shared__ double sh[4][256];
    const int tid = threadIdx.x;
    double a = 0.0, b = 0.0, c = 0.0, d = 0.0;
    for (int i = tid; i < n; i += 256) {
        a += (double)row_out[i * 4 + 0];
        b += (double)row_out[i * 4 + 1];
        c += (double)row_out[i * 4 + 2];
        d += (double)row_out[i * 4 + 3];
    }
    sh[0][tid] = a; sh[1][tid] = b; sh[2][tid] = c; sh[3][tid] = d;
    __syncthreads();
    for (int off = 128; off; off >>= 1) {
        if (tid < off) {
            sh[0][tid] += sh[0][tid + off];
            sh[1][tid] += sh[1][tid + off];
            sh[2][tid] += sh[2][tid + off];
            sh[3][tid] += sh[3][tid + off];
        }
        __syncthreads();
    }
    if (tid == 0) {
        out[0] = (float)(sh[0][0] / (double)n);
        out[1] = (float)(sh[1][0] / (double)n);
        out[2] = (float)(sh[2][0] / ((double)n * (double)(k - 1)));
        out[3] = (float)(sh[3][0] / ((double)n * (double)(n - k)));
    }
}

// ---------------------------------------------------------------------------
extern "C" void kernel_launch(void* const* d_in, const int* in_sizes, int n_in,
                              void* d_out, int out_size, void* d_ws, size_t ws_size,
                              hipStream_t stream) {
    const float* X = (const float*)d_in[0];
    const int n = in_sizes[1];            // 4096
    const int K = in_sizes[0] / n;        // 1024
    const int k = 8;

    float* sim = (float*)d_ws;
    float* row_out = (float*)((char*)d_ws + (size_t)n * n * sizeof(float));

    dim3 gg(n / BN, n / BM);
    gemm_xxt<<<gg, 256, 0, stream>>>(X, sim, n, K);
    row_kernel<<<n / 4, 256, 0, stream>>>(sim, row_out);
    reduce_kernel<<<1, 256, 0, stream>>>(row_out, (float*)d_out, n, k);
}

// Round 3
// 776.221 us; speedup vs baseline: 2.4800x; 2.4800x over previous
//
#include <hip/hip_runtime.h>
#include <math.h>
#include <stdint.h>

// ---------------------------------------------------------------------------
// Threefry2x32 (JAX-compatible) and gumbel mapping (validated rounds 0-1)
// ---------------------------------------------------------------------------
__device__ __forceinline__ uint32_t rotl32(uint32_t v, int r) {
    return (v << r) | (v >> (32 - r));
}

__device__ __forceinline__ void threefry2x32(uint32_t k0, uint32_t k1,
                                             uint32_t& x0, uint32_t& x1) {
    uint32_t ks[3] = {k0, k1, k0 ^ k1 ^ 0x1BD11BDAu};
    const int rot[2][4] = {{13, 15, 26, 6}, {17, 29, 16, 24}};
    x0 += ks[0];
    x1 += ks[1];
#pragma unroll
    for (int i = 0; i < 5; ++i) {
#pragma unroll
        for (int r = 0; r < 4; ++r) {
            x0 += x1;
            x1 = rotl32(x1, rot[i & 1][r]);
            x1 ^= x0;
        }
        x0 += ks[(i + 1) % 3];
        x1 += ks[(i + 2) % 3] + (uint32_t)(i + 1);
    }
}

__device__ __forceinline__ float gumbel_from_bits(uint32_t bits) {
    uint32_t fb = (bits >> 9) | 0x3f800000u;
    float u = __uint_as_float(fb) - 1.0f;
    const float tiny = 1.1754943508222875e-38f;
    u = u * (1.0f - tiny) + tiny;
    u = fmaxf(tiny, u);
    return -logf(-logf(u));
}

__device__ __forceinline__ float softplus_f(float x) {
    return fmaxf(x, 0.0f) + log1pf(expf(-fabsf(x)));
}

// ---------------------------------------------------------------------------
// GEMM: C = X * X^T (unchanged this round)
// ---------------------------------------------------------------------------
#define BM 128
#define BN 128
#define BKK 16

__global__ __launch_bounds__(256) void gemm_xxt(const float* __restrict__ X,
                                                float* __restrict__ C,
                                                int n, int K) {
    __shared__ float As[BKK][BM];
    __shared__ float Bs[BKK][BN];
    const int tid = threadIdx.x;
    const int tx = tid & 15;
    const int ty = tid >> 4;
    const int bm = blockIdx.y * BM;
    const int bn = blockIdx.x * BN;

    float acc[8][8];
#pragma unroll
    for (int p = 0; p < 8; ++p)
#pragma unroll
        for (int q = 0; q < 8; ++q) acc[p][q] = 0.0f;

    for (int k0 = 0; k0 < K; k0 += BKK) {
        for (int l = tid; l < BM * BKK / 4; l += 256) {
            int m = l >> 2;
            int kq = (l & 3) << 2;
            const float4 v = *(const float4*)(X + (size_t)(bm + m) * K + k0 + kq);
            As[kq + 0][m] = v.x; As[kq + 1][m] = v.y;
            As[kq + 2][m] = v.z; As[kq + 3][m] = v.w;
        }
        for (int l = tid; l < BN * BKK / 4; l += 256) {
            int m = l >> 2;
            int kq = (l & 3) << 2;
            const float4 v = *(const float4*)(X + (size_t)(bn + m) * K + k0 + kq);
            Bs[kq + 0][m] = v.x; Bs[kq + 1][m] = v.y;
            Bs[kq + 2][m] = v.z; Bs[kq + 3][m] = v.w;
        }
        __syncthreads();
#pragma unroll
        for (int kk = 0; kk < BKK; ++kk) {
            float a[8], b[8];
#pragma unroll
            for (int p = 0; p < 8; ++p) a[p] = As[kk][p * 16 + ty];
#pragma unroll
            for (int q = 0; q < 8; ++q) b[q] = Bs[kk][q * 16 + tx];
#pragma unroll
            for (int p = 0; p < 8; ++p)
#pragma unroll
                for (int q = 0; q < 8; ++q)
                    acc[p][q] = fmaf(a[p], b[q], acc[p][q]);
        }
        __syncthreads();
    }

    for (int p = 0; p < 8; ++p) {
        int r = bm + p * 16 + ty;
        for (int q = 0; q < 8; ++q) {
            C[(size_t)r * n + bn + q * 16 + tx] = acc[p][q];
        }
    }
}

// ---------------------------------------------------------------------------
// Statically-instantiated bitonic sort network over 4096 elems held as
// v[64] per lane (slot s = lane*64 + r). Template recursion guarantees every
// array index is a compile-time constant -> arrays stay in VGPRs (rule #20).
// ---------------------------------------------------------------------------
template <int KK, int JJ>
__device__ __forceinline__ void bpass(float (&v)[64], const int lane) {
    if constexpr (JJ >= 64) {
        constexpr int L = JJ >> 6;   // lane xor mask
        const bool asc = (lane & (KK >> 6)) == 0;   // KK >= 128 whenever JJ >= 64
        const bool keepmin = ((lane & L) == 0) == asc;
#pragma unroll
        for (int r = 0; r < 64; ++r) {
            float b = __shfl_xor(v[r], L, 64);
            float mn = fminf(v[r], b);
            float mx = fmaxf(v[r], b);
            v[r] = keepmin ? mn : mx;
        }
    } else {
#pragma unroll
        for (int r = 0; r < 64; ++r) {
            if ((r & JJ) == 0) {
                const int r2 = r | JJ;   // compile-time after unroll
                bool asc;
                if constexpr (KK >= 128)     asc = (lane & (KK >> 6)) == 0;
                else if constexpr (KK == 64) asc = (lane & 1) == 0;
                else                         asc = (r & KK) == 0;
                float a = v[r], b = v[r2];
                float mn = fminf(a, b), mx = fmaxf(a, b);
                v[r]  = asc ? mn : mx;
                v[r2] = asc ? mx : mn;
            }
        }
    }
}

template <int KK, int JJ>
__device__ __forceinline__ void bpasses(float (&v)[64], const int lane) {
    bpass<KK, JJ>(v, lane);
    if constexpr (JJ > 1) bpasses<KK, (JJ >> 1)>(v, lane);
}

template <int KK>
__device__ __forceinline__ void bstages(float (&v)[64], const int lane) {
    bpasses<KK, (KK >> 1)>(v, lane);
    if constexpr (KK < 4096) bstages<(KK << 1)>(v, lane);
}

// ---------------------------------------------------------------------------
// Per-row kernel v3: one wave per row, fully register-resident.
// ---------------------------------------------------------------------------
#define NROW 4096
#define NEGN 4088
#define KCLS 8
#define HHALF 8372224u

__global__ __launch_bounds__(256, 1) void row_kernel(const float* __restrict__ sim,
                                                     float* __restrict__ row_out) {
    const int lane = threadIdx.x & 63;
    const int wv = threadIdx.x >> 6;
    const int row = blockIdx.x * 4 + wv;
    const float* simrow = sim + (size_t)row * NROW;
    const int base = row & ~(KCLS - 1);

    float v[64];
    float nsum = 0.0f, psum = 0.0f, plos = 0.0f, pmax = -INFINITY;

    // ---- load: slot s = lane*64 + rq*4 + c holds col = rq*256 + lane*4 + c
#pragma unroll
    for (int rq = 0; rq < 16; ++rq) {
        const float4 w4 = *(const float4*)(simrow + rq * 256 + lane * 4);
        float e[4] = {w4.x, w4.y, w4.z, w4.w};
#pragma unroll
        for (int c = 0; c < 4; ++c) {
            int col = rq * 256 + lane * 4 + c;
            float val = e[c];
            bool ispos = (col >= base) && (col < base + KCLS);
            if (ispos) {
                if (col != row) {
                    psum += val;
                    pmax = fmaxf(pmax, val);
                    plos += softplus_f(-2.0f * (val - 0.5f));
                }
                v[rq * 4 + c] = INFINITY;
            } else {
                nsum += val;
                v[rq * 4 + c] = val;
            }
        }
    }

    // ---- wave butterfly reductions for load-phase stats
#pragma unroll
    for (int off = 1; off < 64; off <<= 1) {
        nsum += __shfl_xor(nsum, off, 64);
        psum += __shfl_xor(psum, off, 64);
        plos += __shfl_xor(plos, off, 64);
        pmax = fmaxf(pmax, __shfl_xor(pmax, off, 64));
    }
    const float m = nsum / (float)NEGN;

    // ---- fully static bitonic sort ascending over s = lane*64 + r
    bstages<2>(v, lane);

    // ---- variance over sorted negatives (positions 0..NEGN-1)
    float vs = 0.0f;
#pragma unroll
    for (int r = 0; r < 64; ++r) {
        bool valid = (r < 56) || (lane < 63);   // s < 4088
        float d = v[r] - m;
        vs += valid ? d * d : 0.0f;
    }
#pragma unroll
    for (int off = 1; off < 64; off <<= 1) vs += __shfl_xor(vs, off, 64);
    const float var = vs / (float)NEGN;
    const float sd = sqrtf(var);
    const float denom = 2.0f * sd * sd;

    // ---- scores: lp(sorted val) + gumbel(sorted position)
    float sc[64];
    const bool lohalf = (row < 2048);
#pragma unroll
    for (int r = 0; r < 64; ++r) {
        bool valid = (r < 56) || (lane < 63);
        uint32_t f = (uint32_t)(row * NEGN + lane * 64 + r);
        uint32_t x0 = lohalf ? f : f - HHALF;
        uint32_t x1 = lohalf ? f + HHALF : f;
        threefry2x32(0u, 42u, x0, x1);
        float g = gumbel_from_bits(lohalf ? x0 : x1);
        float d = v[r] - m;
        sc[r] = valid ? (d * d) / denom + g : -INFINITY;
    }

    // ---- top-7 by repeated wave argmax (tie-break lower index == lax.top_k)
    float nl = 0.0f, neg_last = 0.0f;
    for (int t = 0; t < 7; ++t) {
        float bs = -INFINITY, bv = 0.0f;
        int bi = 0x7fffffff;
#pragma unroll
        for (int r = 0; r < 64; ++r) {
            if (sc[r] > bs) { bs = sc[r]; bv = v[r]; bi = lane * 64 + r; }
        }
#pragma unroll
        for (int off = 1; off < 64; off <<= 1) {
            float os = __shfl_xor(bs, off, 64);
            float ov = __shfl_xor(bv, off, 64);
            int   oi = __shfl_xor(bi, off, 64);
            if (os > bs || (os == bs && oi < bi)) { bs = os; bv = ov; bi = oi; }
        }
        nl += softplus_f(50.0f * (bv - 0.5f));
        if (t == 6) neg_last = bv;
#pragma unroll
        for (int r = 0; r < 64; ++r) {
            if (lane * 64 + r == bi) sc[r] = -INFINITY;
        }
    }

    if (lane == 0) {
        float pos_loss = plos / (float)(KCLS - 1);
        float neg_loss = 0.04f * (nl / (float)(KCLS - 1));
        row_out[row * 4 + 0] = pos_loss + neg_loss;
        row_out[row * 4 + 1] = (pmax > neg_last + 0.05f) ? 1.0f : 0.0f;
        row_out[row * 4 + 2] = psum;
        row_out[row * 4 + 3] = nsum;
    }
}

// ---------------------------------------------------------------------------
// Deterministic final reduction (single block, f64 accumulation)
// ---------------------------------------------------------------------------
__global__ __launch_bounds__(256) void reduce_kernel(const float* __restrict__ row_out,
                                                     float* __restrict__ out,
                                                     int n, int k) {
    __shared__ double sh[4][256];
    const int tid = threadIdx.x;
    double a = 0.0, b = 0.0, c = 0.0, d = 0.0;
    for (int i = tid; i < n; i += 256) {
        a += (double)row_out[i * 4 + 0];
        b += (double)row_out[i * 4 + 1];
        c += (double)row_out[i * 4 + 2];
        d += (double)row_out[i * 4 + 3];
    }
    sh[0][tid] = a; sh[1][tid] = b; sh[2][tid] = c; sh[3][tid] = d;
    __syncthreads();
    for (int off = 128; off; off >>= 1) {
        if (tid < off) {
            sh[0][tid] += sh[0][tid + off];
            sh[1][tid] += sh[1][tid + off];
            sh[2][tid] += sh[2][tid + off];
            sh[3][tid] += sh[3][tid + off];
        }
        __syncthreads();
    }
    if (tid == 0) {
        out[0] = (float)(sh[0][0] / (double)n);
        out[1] = (float)(sh[1][0] / (double)n);
        out[2] = (float)(sh[2][0] / ((double)n * (double)(k - 1)));
        out[3] = (float)(sh[3][0] / ((double)n * (double)(n - k)));
    }
}

// ---------------------------------------------------------------------------
extern "C" void kernel_launch(void* const* d_in, const int* in_sizes, int n_in,
                              void* d_out, int out_size, void* d_ws, size_t ws_size,
                              hipStream_t stream) {
    const float* X = (const float*)d_in[0];
    const int n = in_sizes[1];            // 4096
    const int K = in_sizes[0] / n;        // 1024
    const int k = 8;

    float* sim = (float*)d_ws;
    float* row_out = (float*)((char*)d_ws + (size_t)n * n * sizeof(float));

    dim3 gg(n / BN, n / BM);
    gemm_xxt<<<gg, 256, 0, stream>>>(X, sim, n, K);
    row_kernel<<<n / 4, 256, 0, stream>>>(sim, row_out);
    reduce_kernel<<<1, 256, 0, stream>>>(row_out, (float*)d_out, n, k);
}

// Round 4
// 326.763 us; speedup vs baseline: 5.8913x; 2.3755x over previous
//
#include <hip/hip_runtime.h>
#include <hip/hip_bf16.h>
#include <math.h>
#include <stdint.h>

typedef short bf16x8 __attribute__((ext_vector_type(8)));
typedef float f32x4 __attribute__((ext_vector_type(4)));

// ---------------------------------------------------------------------------
// Threefry2x32 (JAX-compatible) and gumbel mapping (validated rounds 0-3)
// ---------------------------------------------------------------------------
__device__ __forceinline__ uint32_t rotl32(uint32_t v, int r) {
    return (v << r) | (v >> (32 - r));
}

__device__ __forceinline__ void threefry2x32(uint32_t k0, uint32_t k1,
                                             uint32_t& x0, uint32_t& x1) {
    uint32_t ks[3] = {k0, k1, k0 ^ k1 ^ 0x1BD11BDAu};
    const int rot[2][4] = {{13, 15, 26, 6}, {17, 29, 16, 24}};
    x0 += ks[0];
    x1 += ks[1];
#pragma unroll
    for (int i = 0; i < 5; ++i) {
#pragma unroll
        for (int r = 0; r < 4; ++r) {
            x0 += x1;
            x1 = rotl32(x1, rot[i & 1][r]);
            x1 ^= x0;
        }
        x0 += ks[(i + 1) % 3];
        x1 += ks[(i + 2) % 3] + (uint32_t)(i + 1);
    }
}

__device__ __forceinline__ float gumbel_from_bits(uint32_t bits) {
    uint32_t fb = (bits >> 9) | 0x3f800000u;
    float u = __uint_as_float(fb) - 1.0f;
    const float tiny = 1.1754943508222875e-38f;
    u = u * (1.0f - tiny) + tiny;
    u = fmaxf(tiny, u);
    return -logf(-logf(u));
}

__device__ __forceinline__ float softplus_f(float x) {
    return fmaxf(x, 0.0f) + log1pf(expf(-fabsf(x)));
}

// ---------------------------------------------------------------------------
// f32 -> bf16 hi/lo split:  x = hi + lo + O(2^-18 x)
// ---------------------------------------------------------------------------
__global__ __launch_bounds__(256) void convert_kernel(const float* __restrict__ X,
                                                      ushort* __restrict__ Xhi,
                                                      ushort* __restrict__ Xlo,
                                                      int total4) {
    int i = blockIdx.x * 256 + threadIdx.x;
    if (i >= total4) return;
    float4 x = ((const float4*)X)[i];
    float xs[4] = {x.x, x.y, x.z, x.w};
    ushort h[4], l[4];
#pragma unroll
    for (int j = 0; j < 4; ++j) {
        __hip_bfloat16 hb = __float2bfloat16(xs[j]);
        float hf = __bfloat162float(hb);
        __hip_bfloat16 lb = __float2bfloat16(xs[j] - hf);
        h[j] = *(ushort*)&hb;
        l[j] = *(ushort*)&lb;
    }
    ((ushort4*)Xhi)[i] = make_ushort4(h[0], h[1], h[2], h[3]);
    ((ushort4*)Xlo)[i] = make_ushort4(l[0], l[1], l[2], l[3]);
}

// ---------------------------------------------------------------------------
// MFMA GEMM: sim = Hi*Hi^T + Hi*Lo^T + Lo*Hi^T (m97 structure: 128^2 tile,
// BK=32, global_load_lds width-16, linear LDS, 2-barrier K-loop)
// ---------------------------------------------------------------------------
__device__ __forceinline__ void gload_lds16(const void* g, void* l) {
    __builtin_amdgcn_global_load_lds((const __attribute__((address_space(1))) void*)g,
                                     (__attribute__((address_space(3))) void*)l, 16, 0, 0);
}

__global__ __launch_bounds__(256) void gemm_mfma(const ushort* __restrict__ Xhi,
                                                 const ushort* __restrict__ Xlo,
                                                 float* __restrict__ C,
                                                 int n, int K) {
    __shared__ ushort Ah[128][32], Al[128][32], Bh[128][32], Bl[128][32];
    const int tid = threadIdx.x;
    const int lane = tid & 63;
    const int wv = tid >> 6;              // wave 0..3
    const int wr = wv >> 1, wc = wv & 1;  // wave's 64x64 sub-tile
    const int bm = blockIdx.y * 128, bn = blockIdx.x * 128;

    f32x4 acc[4][4];
#pragma unroll
    for (int m = 0; m < 4; ++m)
#pragma unroll
        for (int q = 0; q < 4; ++q) acc[m][q] = {0.f, 0.f, 0.f, 0.f};

    // staging: wave wv covers rows wv*16 + lane/4 (and +64), 16B chunk lane%4
    const int srow = lane >> 2;
    const int scol = (lane & 3) * 8;  // ushort elements
    const size_t rA0 = (size_t)(bm + wv * 16 + srow) * K;
    const size_t rA1 = (size_t)(bm + 64 + wv * 16 + srow) * K;
    const size_t rB0 = (size_t)(bn + wv * 16 + srow) * K;
    const size_t rB1 = (size_t)(bn + 64 + wv * 16 + srow) * K;

    for (int k0 = 0; k0 < K; k0 += 32) {
        gload_lds16(Xhi + rA0 + k0 + scol, &Ah[wv * 16][0]);
        gload_lds16(Xhi + rA1 + k0 + scol, &Ah[64 + wv * 16][0]);
        gload_lds16(Xlo + rA0 + k0 + scol, &Al[wv * 16][0]);
        gload_lds16(Xlo + rA1 + k0 + scol, &Al[64 + wv * 16][0]);
        gload_lds16(Xhi + rB0 + k0 + scol, &Bh[wv * 16][0]);
        gload_lds16(Xhi + rB1 + k0 + scol, &Bh[64 + wv * 16][0]);
        gload_lds16(Xlo + rB0 + k0 + scol, &Bl[wv * 16][0]);
        gload_lds16(Xlo + rB1 + k0 + scol, &Bl[64 + wv * 16][0]);
        __syncthreads();

        bf16x8 ah[4], al[4], bh[4], bl[4];
        const int fr = lane & 15;
        const int kc = (lane >> 4) * 8;
#pragma unroll
        for (int m = 0; m < 4; ++m) {
            ah[m] = *(const bf16x8*)&Ah[wr * 64 + m * 16 + fr][kc];
            al[m] = *(const bf16x8*)&Al[wr * 64 + m * 16 + fr][kc];
            bh[m] = *(const bf16x8*)&Bh[wc * 64 + m * 16 + fr][kc];
            bl[m] = *(const bf16x8*)&Bl[wc * 64 + m * 16 + fr][kc];
        }
#pragma unroll
        for (int m = 0; m < 4; ++m)
#pragma unroll
            for (int q = 0; q < 4; ++q) {
                acc[m][q] = __builtin_amdgcn_mfma_f32_16x16x32_bf16(ah[m], bh[q], acc[m][q], 0, 0, 0);
                acc[m][q] = __builtin_amdgcn_mfma_f32_16x16x32_bf16(ah[m], bl[q], acc[m][q], 0, 0, 0);
                acc[m][q] = __builtin_amdgcn_mfma_f32_16x16x32_bf16(al[m], bh[q], acc[m][q], 0, 0, 0);
            }
        __syncthreads();
    }

    // C/D layout (m89-verified): col = lane&15, row = (lane>>4)*4 + reg
    const int cr = (lane >> 4) * 4;
    const int cc = lane & 15;
#pragma unroll
    for (int m = 0; m < 4; ++m)
#pragma unroll
        for (int q = 0; q < 4; ++q) {
            const int r0 = bm + wr * 64 + m * 16 + cr;
            const int c0 = bn + wc * 64 + q * 16 + cc;
#pragma unroll
            for (int j = 0; j < 4; ++j)
                C[(size_t)(r0 + j) * n + c0] = acc[m][q][j];
        }
}

// ---------------------------------------------------------------------------
// Fallback f32 vector GEMM (used only if ws_size is too small for hi/lo)
// ---------------------------------------------------------------------------
#define BM 128
#define BN 128
#define BKK 16

__global__ __launch_bounds__(256) void gemm_xxt(const float* __restrict__ X,
                                                float* __restrict__ C,
                                                int n, int K) {
    __shared__ float As[BKK][BM];
    __shared__ float Bs[BKK][BN];
    const int tid = threadIdx.x;
    const int tx = tid & 15;
    const int ty = tid >> 4;
    const int bm = blockIdx.y * BM;
    const int bn = blockIdx.x * BN;

    float acc[8][8];
#pragma unroll
    for (int p = 0; p < 8; ++p)
#pragma unroll
        for (int q = 0; q < 8; ++q) acc[p][q] = 0.0f;

    for (int k0 = 0; k0 < K; k0 += BKK) {
        for (int l = tid; l < BM * BKK / 4; l += 256) {
            int m = l >> 2;
            int kq = (l & 3) << 2;
            const float4 v = *(const float4*)(X + (size_t)(bm + m) * K + k0 + kq);
            As[kq + 0][m] = v.x; As[kq + 1][m] = v.y;
            As[kq + 2][m] = v.z; As[kq + 3][m] = v.w;
        }
        for (int l = tid; l < BN * BKK / 4; l += 256) {
            int m = l >> 2;
            int kq = (l & 3) << 2;
            const float4 v = *(const float4*)(X + (size_t)(bn + m) * K + k0 + kq);
            Bs[kq + 0][m] = v.x; Bs[kq + 1][m] = v.y;
            Bs[kq + 2][m] = v.z; Bs[kq + 3][m] = v.w;
        }
        __syncthreads();
#pragma unroll
        for (int kk = 0; kk < BKK; ++kk) {
            float a[8], b[8];
#pragma unroll
            for (int p = 0; p < 8; ++p) a[p] = As[kk][p * 16 + ty];
#pragma unroll
            for (int q = 0; q < 8; ++q) b[q] = Bs[kk][q * 16 + tx];
#pragma unroll
            for (int p = 0; p < 8; ++p)
#pragma unroll
                for (int q = 0; q < 8; ++q)
                    acc[p][q] = fmaf(a[p], b[q], acc[p][q]);
        }
        __syncthreads();
    }

    for (int p = 0; p < 8; ++p) {
        int r = bm + p * 16 + ty;
        for (int q = 0; q < 8; ++q) {
            C[(size_t)r * n + bn + q * 16 + tx] = acc[p][q];
        }
    }
}

// ---------------------------------------------------------------------------
// Statically-instantiated bitonic sort network (validated round 3)
// ---------------------------------------------------------------------------
template <int KK, int JJ>
__device__ __forceinline__ void bpass(float (&v)[64], const int lane) {
    if constexpr (JJ >= 64) {
        constexpr int L = JJ >> 6;
        const bool asc = (lane & (KK >> 6)) == 0;
        const bool keepmin = ((lane & L) == 0) == asc;
#pragma unroll
        for (int r = 0; r < 64; ++r) {
            float b = __shfl_xor(v[r], L, 64);
            float mn = fminf(v[r], b);
            float mx = fmaxf(v[r], b);
            v[r] = keepmin ? mn : mx;
        }
    } else {
#pragma unroll
        for (int r = 0; r < 64; ++r) {
            if ((r & JJ) == 0) {
                const int r2 = r | JJ;
                bool asc;
                if constexpr (KK >= 128)     asc = (lane & (KK >> 6)) == 0;
                else if constexpr (KK == 64) asc = (lane & 1) == 0;
                else                         asc = (r & KK) == 0;
                float a = v[r], b = v[r2];
                float mn = fminf(a, b), mx = fmaxf(a, b);
                v[r]  = asc ? mn : mx;
                v[r2] = asc ? mx : mn;
            }
        }
    }
}

template <int KK, int JJ>
__device__ __forceinline__ void bpasses(float (&v)[64], const int lane) {
    bpass<KK, JJ>(v, lane);
    if constexpr (JJ > 1) bpasses<KK, (JJ >> 1)>(v, lane);
}

template <int KK>
__device__ __forceinline__ void bstages(float (&v)[64], const int lane) {
    bpasses<KK, (KK >> 1)>(v, lane);
    if constexpr (KK < 4096) bstages<(KK << 1)>(v, lane);
}

// ---------------------------------------------------------------------------
// Per-row kernel: one wave per row, fully register-resident (validated r3)
// ---------------------------------------------------------------------------
#define NROW 4096
#define NEGN 4088
#define KCLS 8
#define HHALF 8372224u

__global__ __launch_bounds__(256, 1) void row_kernel(const float* __restrict__ sim,
                                                     float* __restrict__ row_out) {
    const int lane = threadIdx.x & 63;
    const int wv = threadIdx.x >> 6;
    const int row = blockIdx.x * 4 + wv;
    const float* simrow = sim + (size_t)row * NROW;
    const int base = row & ~(KCLS - 1);

    float v[64];
    float nsum = 0.0f, psum = 0.0f, plos = 0.0f, pmax = -INFINITY;

#pragma unroll
    for (int rq = 0; rq < 16; ++rq) {
        const float4 w4 = *(const float4*)(simrow + rq * 256 + lane * 4);
        float e[4] = {w4.x, w4.y, w4.z, w4.w};
#pragma unroll
        for (int c = 0; c < 4; ++c) {
            int col = rq * 256 + lane * 4 + c;
            float val = e[c];
            bool ispos = (col >= base) && (col < base + KCLS);
            if (ispos) {
                if (col != row) {
                    psum += val;
                    pmax = fmaxf(pmax, val);
                    plos += softplus_f(-2.0f * (val - 0.5f));
                }
                v[rq * 4 + c] = INFINITY;
            } else {
                nsum += val;
                v[rq * 4 + c] = val;
            }
        }
    }

#pragma unroll
    for (int off = 1; off < 64; off <<= 1) {
        nsum += __shfl_xor(nsum, off, 64);
        psum += __shfl_xor(psum, off, 64);
        plos += __shfl_xor(plos, off, 64);
        pmax = fmaxf(pmax, __shfl_xor(pmax, off, 64));
    }
    const float m = nsum / (float)NEGN;

    bstages<2>(v, lane);

    float vs = 0.0f;
#pragma unroll
    for (int r = 0; r < 64; ++r) {
        bool valid = (r < 56) || (lane < 63);
        float d = v[r] - m;
        vs += valid ? d * d : 0.0f;
    }
#pragma unroll
    for (int off = 1; off < 64; off <<= 1) vs += __shfl_xor(vs, off, 64);
    const float var = vs / (float)NEGN;
    const float sd = sqrtf(var);
    const float denom = 2.0f * sd * sd;

    float sc[64];
    const bool lohalf = (row < 2048);
#pragma unroll
    for (int r = 0; r < 64; ++r) {
        bool valid = (r < 56) || (lane < 63);
        uint32_t f = (uint32_t)(row * NEGN + lane * 64 + r);
        uint32_t x0 = lohalf ? f : f - HHALF;
        uint32_t x1 = lohalf ? f + HHALF : f;
        threefry2x32(0u, 42u, x0, x1);
        float g = gumbel_from_bits(lohalf ? x0 : x1);
        float d = v[r] - m;
        sc[r] = valid ? (d * d) / denom + g : -INFINITY;
    }

    float nl = 0.0f, neg_last = 0.0f;
    for (int t = 0; t < 7; ++t) {
        float bs = -INFINITY, bv = 0.0f;
        int bi = 0x7fffffff;
#pragma unroll
        for (int r = 0; r < 64; ++r) {
            if (sc[r] > bs) { bs = sc[r]; bv = v[r]; bi = lane * 64 + r; }
        }
#pragma unroll
        for (int off = 1; off < 64; off <<= 1) {
            float os = __shfl_xor(bs, off, 64);
            float ov = __shfl_xor(bv, off, 64);
            int   oi = __shfl_xor(bi, off, 64);
            if (os > bs || (os == bs && oi < bi)) { bs = os; bv = ov; bi = oi; }
        }
        nl += softplus_f(50.0f * (bv - 0.5f));
        if (t == 6) neg_last = bv;
#pragma unroll
        for (int r = 0; r < 64; ++r) {
            if (lane * 64 + r == bi) sc[r] = -INFINITY;
        }
    }

    if (lane == 0) {
        float pos_loss = plos / (float)(KCLS - 1);
        float neg_loss = 0.04f * (nl / (float)(KCLS - 1));
        row_out[row * 4 + 0] = pos_loss + neg_loss;
        row_out[row * 4 + 1] = (pmax > neg_last + 0.05f) ? 1.0f : 0.0f;
        row_out[row * 4 + 2] = psum;
        row_out[row * 4 + 3] = nsum;
    }
}

// ---------------------------------------------------------------------------
// Deterministic final reduction (single block, f64 accumulation)
// ---------------------------------------------------------------------------
__global__ __launch_bounds__(256) void reduce_kernel(const float* __restrict__ row_out,
                                                     float* __restrict__ out,
                                                     int n, int k) {
    __shared__ double sh[4][256];
    const int tid = threadIdx.x;
    double a = 0.0, b = 0.0, c = 0.0, d = 0.0;
    for (int i = tid; i < n; i += 256) {
        a += (double)row_out[i * 4 + 0];
        b += (double)row_out[i * 4 + 1];
        c += (double)row_out[i * 4 + 2];
        d += (double)row_out[i * 4 + 3];
    }
    sh[0][tid] = a; sh[1][tid] = b; sh[2][tid] = c; sh[3][tid] = d;
    __syncthreads();
    for (int off = 128; off; off >>= 1) {
        if (tid < off) {
            sh[0][tid] += sh[0][tid + off];
            sh[1][tid] += sh[1][tid + off];
            sh[2][tid] += sh[2][tid + off];
            sh[3][tid] += sh[3][tid + off];
        }
        __syncthreads();
    }
    if (tid == 0) {
        out[0] = (float)(sh[0][0] / (double)n);
        out[1] = (float)(sh[1][0] / (double)n);
        out[2] = (float)(sh[2][0] / ((double)n * (double)(k - 1)));
        out[3] = (float)(sh[3][0] / ((double)n * (double)(n - k)));
    }
}

// ---------------------------------------------------------------------------
extern "C" void kernel_launch(void* const* d_in, const int* in_sizes, int n_in,
                              void* d_out, int out_size, void* d_ws, size_t ws_size,
                              hipStream_t stream) {
    const float* X = (const float*)d_in[0];
    const int n = in_sizes[1];            // 4096
    const int K = in_sizes[0] / n;        // 1024
    const int k = 8;

    const size_t simB = (size_t)n * n * sizeof(float);      // 64 MB
    const size_t rowB = (size_t)n * 4 * sizeof(float);      // 64 KB
    float* sim = (float*)d_ws;
    float* row_out = (float*)((char*)d_ws + simB);
    ushort* Xhi = (ushort*)((char*)d_ws + simB + rowB);
    ushort* Xlo = Xhi + (size_t)n * K;
    const size_t need = simB + rowB + (size_t)n * K * 2 * sizeof(ushort);

    if (ws_size >= need) {
        const int total4 = n * K / 4;
        convert_kernel<<<(total4 + 255) / 256, 256, 0, stream>>>(X, Xhi, Xlo, total4);
        dim3 gg(n / 128, n / 128);
        gemm_mfma<<<gg, 256, 0, stream>>>(Xhi, Xlo, sim, n, K);
    } else {
        dim3 gg(n / BN, n / BM);
        gemm_xxt<<<gg, 256, 0, stream>>>(X, sim, n, K);
    }
    row_kernel<<<n / 4, 256, 0, stream>>>(sim, row_out);
    reduce_kernel<<<1, 256, 0, stream>>>(row_out, (float*)d_out, n, k);
}